// Round 9
// baseline (188.260 us; speedup 1.0000x reference)
//
#include <hip/hip_runtime.h>
#include <hip/hip_bf16.h>

// Problem constants
#define BB 8
#define TT 2048
#define CC 1024
#define HH 64

// DIAGNOSTIC BUILD: main loops repeated 4x with opaque-zero accumulator reset
// (bit-identical output, no DCE) so qkv/attn surface above the ~39us harness
// fill dispatches in rocprof top-5 and we finally read their counters.
#define REPS 4

typedef float f32x4 __attribute__((ext_vector_type(4)));
typedef float f32x16 __attribute__((ext_vector_type(16)));
typedef short s16x8 __attribute__((ext_vector_type(8)));   // 8 bf16 in 4 VGPRs

// fp32 -> bf16 (RNE), pure bit math
static __device__ __forceinline__ unsigned short f2bf(float f) {
    unsigned int u = __float_as_uint(f);
    u = (u + 0x7FFFu + ((u >> 16) & 1u)) >> 16;
    return (unsigned short)u;
}

// pack two f32 -> 2 bf16 in one dword (RNE); dst.lo = src0, dst.hi = src1
static __device__ __forceinline__ unsigned cvt_pk_bf16(float lo, float hi) {
    unsigned r;
    asm("v_cvt_pk_bf16_f32 %0, %1, %2" : "=v"(r) : "v"(lo), "v"(hi));
    return r;
}

// ---------------------------------------------------------------------------
// Kernel 0: pack Wq|Wk|Wv [1024][64] fp32 into MFMA B-fragment order, bf16.
// ---------------------------------------------------------------------------
__global__ __launch_bounds__(256) void wt_kernel(
    const float* __restrict__ Wq, const float* __restrict__ Wk,
    const float* __restrict__ Wv, unsigned short* __restrict__ wTf) {
    const int e8 = blockIdx.x * 256 + threadIdx.x;
    const int lane = e8 & 63;
    const int s = (e8 >> 6) & 31;
    const int n16 = e8 >> 11;        // 0..11
    const int sel = n16 >> 2;
    const float* W = (sel == 0) ? Wq : ((sel == 1) ? Wk : Wv);
    const int h = ((n16 & 3) << 4) + (lane & 15);
    const int cb = s * 32 + ((lane >> 4) << 3);
    s16x8 v;
#pragma unroll
    for (int j = 0; j < 8; ++j) v[j] = (short)f2bf(W[(size_t)(cb + j) * HH + h]);
    *reinterpret_cast<s16x8*>(&wTf[(size_t)e8 * 8]) = v;
}

// ---------------------------------------------------------------------------
// Kernel 1: QKV projection GEMM (round-7 v3 structure, x REPS diagnostic).
// 256 blocks x 8 waves; block = 64 rows; wave = 32 rows x 48 cols; BK=128.
// ---------------------------------------------------------------------------
__global__ __launch_bounds__(512, 2) void qkv_kernel(
    const float* __restrict__ x, const unsigned short* __restrict__ wTf,
    unsigned short* __restrict__ Qf, unsigned short* __restrict__ Kf,
    unsigned short* __restrict__ Vf) {
    __shared__ unsigned short xb[2][64 * 128];   // 2 x 16 KB bf16, XOR-swizzled
    const int tid = threadIdx.x;
    const int wv = tid >> 6, lane = tid & 63;
    const int lo = lane & 15, hi = lane >> 4;
    const int wm = wv >> 2, wn = wv & 3;
    const int rb = blockIdx.x * 64;
    const float zf = (float)(blockIdx.x >> 30);   // opaque 0

    const int srow = tid >> 3, sc = (tid & 7) * 16;
    const float* xsrc = &x[(size_t)(rb + srow) * CC + sc];
    const int swz = (srow & 7) << 3;
    const int wg0 = srow * 128 + (sc ^ swz);
    const int wg1 = srow * 128 + ((sc + 8) ^ swz);

    const int ar0 = (wm * 32 + lo) * 128;
    const int ar1 = ar0 + 16 * 128;
    const int aswz = (lo & 7) << 3;

    f32x4 acc[2][3];
#pragma unroll
    for (int m = 0; m < 2; ++m)
#pragma unroll
        for (int n = 0; n < 3; ++n) acc[m][n] = (f32x4){0.f, 0.f, 0.f, 0.f};

    f32x4 pf[4];
    s16x8 bv[3][3];
#define BLOAD(SET, SLOT)                                                       \
    {                                                                          \
        _Pragma("unroll")                                                      \
        for (int n = 0; n < 3; ++n)                                            \
            bv[SET][n] = *reinterpret_cast<const s16x8*>(                      \
                &wTf[(((size_t)(wn * 3 + n) * 32 + (SLOT)) * 64 + lane) * 8]); \
    }

    for (int rep = 0; rep < REPS; ++rep) {
        // opaque restart: acc *= 0 (true dependence, no DCE, exact zeros)
#pragma unroll
        for (int m = 0; m < 2; ++m)
#pragma unroll
            for (int n = 0; n < 3; ++n) acc[m][n] *= zf;
        // prefetch chunk 0
#pragma unroll
        for (int i = 0; i < 4; ++i) pf[i] = *reinterpret_cast<const f32x4*>(xsrc + 4 * i);
        BLOAD(0, 0)
        BLOAD(1, 1)

#pragma unroll
        for (int c = 0; c < 8; ++c) {
            unsigned short* wb = xb[c & 1];
            s16x8 w0, w1;
            w0[0] = (short)f2bf(pf[0][0]); w0[1] = (short)f2bf(pf[0][1]);
            w0[2] = (short)f2bf(pf[0][2]); w0[3] = (short)f2bf(pf[0][3]);
            w0[4] = (short)f2bf(pf[1][0]); w0[5] = (short)f2bf(pf[1][1]);
            w0[6] = (short)f2bf(pf[1][2]); w0[7] = (short)f2bf(pf[1][3]);
            w1[0] = (short)f2bf(pf[2][0]); w1[1] = (short)f2bf(pf[2][1]);
            w1[2] = (short)f2bf(pf[2][2]); w1[3] = (short)f2bf(pf[2][3]);
            w1[4] = (short)f2bf(pf[3][0]); w1[5] = (short)f2bf(pf[3][1]);
            w1[6] = (short)f2bf(pf[3][2]); w1[7] = (short)f2bf(pf[3][3]);
            *reinterpret_cast<s16x8*>(&wb[wg0]) = w0;
            *reinterpret_cast<s16x8*>(&wb[wg1]) = w1;
            __syncthreads();
            if (c < 7) {
#pragma unroll
                for (int i = 0; i < 4; ++i)
                    pf[i] = *reinterpret_cast<const f32x4*>(xsrc + (c + 1) * 128 + 4 * i);
            }
            const unsigned short* base = xb[c & 1];
#pragma unroll
            for (int kh = 0; kh < 4; ++kh) {
                const int slot = c * 4 + kh;
                if (slot + 2 < 32) BLOAD((slot + 2) % 3, slot + 2)
                const s16x8 a0 = *reinterpret_cast<const s16x8*>(
                    &base[ar0 + ((kh * 32 + hi * 8) ^ aswz)]);
                const s16x8 a1 = *reinterpret_cast<const s16x8*>(
                    &base[ar1 + ((kh * 32 + hi * 8) ^ aswz)]);
#pragma unroll
                for (int n = 0; n < 3; ++n) {
                    acc[0][n] = __builtin_amdgcn_mfma_f32_16x16x32_bf16(a0, bv[slot % 3][n], acc[0][n], 0, 0, 0);
                    acc[1][n] = __builtin_amdgcn_mfma_f32_16x16x32_bf16(a1, bv[slot % 3][n], acc[1][n], 0, 0, 0);
                }
            }
        }
    }
#undef BLOAD

    // Epilogue -> fragment layouts. C/D: col=16*n16+lo, row=rb+wm*32+m*16+4*hi+r
#pragma unroll
    for (int n = 0; n < 3; ++n) {
        const int n16 = wn * 3 + n;
        const int sel = n16 >> 2;
#pragma unroll
        for (int m = 0; m < 2; ++m) {
#pragma unroll
            for (int r = 0; r < 4; ++r) {
                const int row = rb + wm * 32 + m * 16 + 4 * hi + r;
                const int b_ = row >> 11, tok = row & (TT - 1);
                const int tile = tok >> 5;
                const unsigned short bvv = f2bf(acc[m][n][r]);
                if (sel == 0) {
                    const int s = n16, half = (lo >> 3) & 1, j = lo & 7;
                    Qf[((((size_t)b_ * 64 + tile) * 4 + s) * 64 + half * 32 + (tok & 31)) * 8 + j] = bvv;
                } else if (sel == 1) {
                    const int s = n16 - 4, half = (lo >> 3) & 1, j = lo & 7;
                    Kf[((((size_t)b_ * 64 + tile) * 4 + s) * 64 + half * 32 + (tok & 31)) * 8 + j] = bvv;
                } else {
                    const int h = (n16 - 8) * 16 + lo;
                    const int mt = h >> 5;
                    const int tt = tok & 31;
                    const int s2 = tt >> 4, hf = (tt >> 3) & 1, jj = tt & 7;
                    Vf[(((((size_t)b_ * 64 + tile) * 2 + mt) * 2 + s2) * 64 + hf * 32 + (h & 31)) * 8 + jj] = bvv;
                }
            }
        }
    }
}

// ---------------------------------------------------------------------------
// Kernel 2: flash attention (round-7 structure, x REPS diagnostic).
// 512 blocks (8 batch x 64 q-tiles of 32 rows) x 8 waves, kv tiles strided.
// ---------------------------------------------------------------------------
__global__ __launch_bounds__(512, 4) void attn_kernel(
    const unsigned short* __restrict__ Qf, const unsigned short* __restrict__ Kf,
    const unsigned short* __restrict__ Vf, float* __restrict__ out) {
    __shared__ __align__(16) char smem[33792 + 2048];   // 35.8 KB
    float (*OfL)[64][33] = reinterpret_cast<float(*)[64][33]>(smem);   // 4 slots
    float (*Mm)[32] = reinterpret_cast<float(*)[32]>(smem + 33792);
    float (*Ml)[32] = reinterpret_cast<float(*)[32]>(smem + 33792 + 1024);

    const int tid = threadIdx.x;
    const int wv = tid >> 6, lane = tid & 63;
    const int q = lane & 31, half = lane >> 5;
    const int b = blockIdx.x & 7;              // batch -> XCD L2 locality
    const int qt = 63 - (blockIdx.x >> 3);     // largest work first
    const int qbase = qt * 32;
    const float CEXP = 0.125f * 1.44269504f;   // scale * log2(e)
    const float zf = (float)(blockIdx.x >> 30);   // opaque 0

    // Q fragments: one 1KB coalesced load per s
    const unsigned short* qp = &Qf[(((size_t)b * 64 + qt) * 256 + lane) * 8];
    s16x8 qf[4];
#pragma unroll
    for (int s = 0; s < 4; ++s) qf[s] = *reinterpret_cast<const s16x8*>(qp + s * 512);

    f32x16 oA, oB;   // O^T h-blocks [0..31],[32..63]; lane holds col q
#pragma unroll
    for (int r = 0; r < 16; ++r) { oA[r] = 0.f; oB[r] = 0.f; }
    float m = -1e30f, l = 0.f;   // raw-score domain

    for (int rep = 0; rep < REPS; ++rep) {
        // opaque restart (true dependence on previous rep -> no DCE; exact)
        m = -1e30f + zf * l;
        l = zf * l;
#pragma unroll
        for (int r = 0; r < 16; ++r) { oA[r] *= zf; oB[r] *= zf; }

        for (int t = wv; t <= qt; t += 8) {
            // V fragments (issued early, contiguous)
            const unsigned short* vp = &Vf[(((size_t)b * 64 + t) * 256 + lane) * 8];
            s16x8 vf[4];
#pragma unroll
            for (int i = 0; i < 4; ++i)
                vf[i] = *reinterpret_cast<const s16x8*>(vp + i * 512);
            // K fragments + QK^T -> S^T[key][q]
            const unsigned short* kp = &Kf[(((size_t)b * 64 + t) * 256 + lane) * 8];
            f32x16 sa;
#pragma unroll
            for (int r = 0; r < 16; ++r) sa[r] = 0.f;
#pragma unroll
            for (int s = 0; s < 4; ++s) {
                const s16x8 kf = *reinterpret_cast<const s16x8*>(kp + s * 512);
                sa = __builtin_amdgcn_mfma_f32_32x32x16_bf16(kf, qf[s], sa, 0, 0, 0);
            }
            // causal mask on diagonal tile: key(r) = 4*half + (r&3) + 8*(r>>2)
            if (t == qt) {
#pragma unroll
                for (int r = 0; r < 16; ++r) {
                    const int key = 4 * half + (r & 3) + 8 * (r >> 2);
                    if (key > q) sa[r] = -1e30f;
                }
            }
            // row max: in-lane tree + partner exchange
            float pmax = sa[0];
#pragma unroll
            for (int r = 1; r < 16; ++r) pmax = fmaxf(pmax, sa[r]);
            pmax = fmaxf(pmax, __shfl_xor(pmax, 32));
            // defer-max: raw thr 64 = 8 in exp units -> P bounded by e^8
            if (!__all(pmax <= m + 64.f)) {
                const float mnew = fmaxf(m, pmax);
                const float alpha = exp2f((m - mnew) * CEXP);
                l *= alpha;
#pragma unroll
                for (int r = 0; r < 16; ++r) { oA[r] *= alpha; oB[r] *= alpha; }
                m = mnew;
            }
            // exp + row sum
            float rs = 0.f;
#pragma unroll
            for (int r = 0; r < 16; ++r) {
                const float p = exp2f((sa[r] - m) * CEXP);
                sa[r] = p;
                rs += p;
            }
            l += rs + __shfl_xor(rs, 32);
            // pack P -> bf16 pairs; exchange only the 4 words the partner needs
            unsigned d[8];
#pragma unroll
            for (int i = 0; i < 8; ++i) d[i] = cvt_pk_bf16(sa[2 * i], sa[2 * i + 1]);
            const unsigned snd0 = half ? d[0] : d[2];
            const unsigned snd1 = half ? d[1] : d[3];
            const unsigned snd2 = half ? d[4] : d[6];
            const unsigned snd3 = half ? d[5] : d[7];
            const unsigned rcv0 = __shfl_xor(snd0, 32);
            const unsigned rcv1 = __shfl_xor(snd1, 32);
            const unsigned rcv2 = __shfl_xor(snd2, 32);
            const unsigned rcv3 = __shfl_xor(snd3, 32);
            union { unsigned u[4]; s16x8 v; } f0, f1;
            f0.u[0] = half ? rcv0 : d[0];
            f0.u[1] = half ? rcv1 : d[1];
            f0.u[2] = half ? d[2] : rcv0;
            f0.u[3] = half ? d[3] : rcv1;
            f1.u[0] = half ? rcv2 : d[4];
            f1.u[1] = half ? rcv3 : d[5];
            f1.u[2] = half ? d[6] : rcv2;
            f1.u[3] = half ? d[7] : rcv3;
            // PV: O^T += V^T @ P^T  (two K=16 steps, two h-blocks)
            oA = __builtin_amdgcn_mfma_f32_32x32x16_bf16(vf[0], f0.v, oA, 0, 0, 0);
            oB = __builtin_amdgcn_mfma_f32_32x32x16_bf16(vf[2], f0.v, oB, 0, 0, 0);
            oA = __builtin_amdgcn_mfma_f32_32x32x16_bf16(vf[1], f1.v, oA, 0, 0, 0);
            oB = __builtin_amdgcn_mfma_f32_32x32x16_bf16(vf[3], f1.v, oB, 0, 0, 0);
        }
    }

    // ---- tree combine of 8 partials ----
#define PUBLISH(slot)                                                      \
    {                                                                      \
        _Pragma("unroll")                                                  \
        for (int r = 0; r < 16; ++r) {                                     \
            const int h0 = (r & 3) + 8 * (r >> 2) + 4 * half;              \
            OfL[slot][h0][q] = oA[r];                                      \
            OfL[slot][h0 + 32][q] = oB[r];                                 \
        }                                                                  \
    }
#define MERGE(slot, srcw)                                                  \
    {                                                                      \
        const float mb = Mm[srcw][q], lb = Ml[srcw][q];                    \
        const float M = fmaxf(m, mb);                                      \
        const float wa = exp2f((m - M) * CEXP);                            \
        const float wb = exp2f((mb - M) * CEXP);                           \
        _Pragma("unroll")                                                  \
        for (int r = 0; r < 16; ++r) {                                     \
            const int h0 = (r & 3) + 8 * (r >> 2) + 4 * half;              \
            oA[r] = oA[r] * wa + OfL[slot][h0][q] * wb;                    \
            oB[r] = oB[r] * wa + OfL[slot][h0 + 32][q] * wb;               \
        }                                                                  \
        l = l * wa + lb * wb;                                              \
        m = M;                                                             \
    }

    if (lane < 32) { Mm[wv][q] = m; Ml[wv][q] = l; }
    if (wv >= 4) PUBLISH(wv - 4);
    __syncthreads();
    if (wv < 4) MERGE(wv, wv + 4);
    __syncthreads();
    if (wv == 2 || wv == 3) {
        PUBLISH(wv - 2);
        if (lane < 32) { Mm[wv][q] = m; Ml[wv][q] = l; }
    }
    __syncthreads();
    if (wv < 2) MERGE(wv, wv + 2);
    __syncthreads();
    if (wv == 1) {
        PUBLISH(1);
        if (lane < 32) { Mm[1][q] = m; Ml[1][q] = l; }
    }
    __syncthreads();
    if (wv == 0) {
        MERGE(1, 1);
        const float inv = 1.f / l;
#pragma unroll
        for (int r = 0; r < 16; ++r) {
            const int h0 = (r & 3) + 8 * (r >> 2) + 4 * half;
            OfL[0][h0][q] = oA[r] * inv;
            OfL[0][h0 + 32][q] = oB[r] * inv;
        }
    }
    __syncthreads();
    // coalesced final write
#pragma unroll
    for (int i = 0; i < 4; ++i) {
        const int idx = tid + 512 * i;
        const int h = idx & 63, q2 = idx >> 6;
        out[((size_t)b * TT + qbase + q2) * HH + h] = OfL[0][h][q2];
    }
#undef PUBLISH
#undef MERGE
}

extern "C" void kernel_launch(void* const* d_in, const int* in_sizes, int n_in,
                              void* d_out, int out_size, void* d_ws, size_t ws_size,
                              hipStream_t stream) {
    (void)in_sizes; (void)n_in; (void)out_size; (void)ws_size;
    const float* x  = (const float*)d_in[0];
    const float* Wq = (const float*)d_in[1];
    const float* Wk = (const float*)d_in[2];
    const float* Wv = (const float*)d_in[3];
    float* out = (float*)d_out;

    char* ws = (char*)d_ws;
    unsigned short* wTf = (unsigned short*)ws;                      // 384 KB
    unsigned short* Qf  = (unsigned short*)(ws + 393216);           // 2 MB
    unsigned short* Kf  = (unsigned short*)(ws + 393216 + 2097152); // 2 MB
    unsigned short* Vf  = (unsigned short*)(ws + 393216 + 4194304); // 2 MB

    wt_kernel<<<96, 256, 0, stream>>>(Wq, Wk, Wv, wTf);
    qkv_kernel<<<256, 512, 0, stream>>>(x, wTf, Qf, Kf, Vf);
    attn_kernel<<<512, 512, 0, stream>>>(Qf, Kf, Vf, out);
}

// Round 10
// 52.841 us; speedup vs baseline: 3.5628x; 3.5628x over previous
//
#include <hip/hip_runtime.h>
#include <hip/hip_bf16.h>

// Problem constants
#define BB 8
#define TT 2048
#define CC 1024
#define HH 64

typedef float f32x4 __attribute__((ext_vector_type(4)));
typedef float f32x16 __attribute__((ext_vector_type(16)));
typedef short s16x8 __attribute__((ext_vector_type(8)));   // 8 bf16 in 4 VGPRs

// fp32 -> bf16 (RNE), pure bit math
static __device__ __forceinline__ unsigned short f2bf(float f) {
    unsigned int u = __float_as_uint(f);
    u = (u + 0x7FFFu + ((u >> 16) & 1u)) >> 16;
    return (unsigned short)u;
}

// pack two f32 -> 2 bf16 in one dword (RNE); dst.lo = src0, dst.hi = src1
static __device__ __forceinline__ unsigned cvt_pk_bf16(float lo, float hi) {
    unsigned r;
    asm("v_cvt_pk_bf16_f32 %0, %1, %2" : "=v"(r) : "v"(lo), "v"(hi));
    return r;
}

// ---------------------------------------------------------------------------
// Kernel 0: pack Wq|Wk|Wv [1024][64] fp32 into MFMA B-fragment order, bf16.
// ---------------------------------------------------------------------------
__global__ __launch_bounds__(256) void wt_kernel(
    const float* __restrict__ Wq, const float* __restrict__ Wk,
    const float* __restrict__ Wv, unsigned short* __restrict__ wTf) {
    const int e8 = blockIdx.x * 256 + threadIdx.x;
    const int lane = e8 & 63;
    const int s = (e8 >> 6) & 31;
    const int n16 = e8 >> 11;        // 0..11
    const int sel = n16 >> 2;
    const float* W = (sel == 0) ? Wq : ((sel == 1) ? Wk : Wv);
    const int h = ((n16 & 3) << 4) + (lane & 15);
    const int cb = s * 32 + ((lane >> 4) << 3);
    s16x8 v;
#pragma unroll
    for (int j = 0; j < 8; ++j) v[j] = (short)f2bf(W[(size_t)(cb + j) * HH + h]);
    *reinterpret_cast<s16x8*>(&wTf[(size_t)e8 * 8]) = v;
}

// ---------------------------------------------------------------------------
// Kernel 1: QKV projection GEMM v5.
// 512 blocks x 8 waves; block = 32 rows = ONE attn tile. BK=256, 4 chunks,
// dbuf LDS, one barrier/chunk, 2 blocks/CU (drain overlap). Wave (wm,wn):
// 16 rows x 3 n16. Epilogue: acc -> LDS fragment image (2B LDS scatter) ->
// coalesced 16B global stores (kills the 131MB->12MB write amplification).
// ---------------------------------------------------------------------------
__global__ __launch_bounds__(512, 4) void qkv_kernel(
    const float* __restrict__ x, const unsigned short* __restrict__ wTf,
    unsigned short* __restrict__ Qf, unsigned short* __restrict__ Kf,
    unsigned short* __restrict__ Vf) {
    __shared__ unsigned short xb[2][32 * 256];   // 2 x 16 KB bf16, XOR-swizzled
    const int tid = threadIdx.x;
    const int wv = tid >> 6, lane = tid & 63;
    const int lo = lane & 15, hi = lane >> 4;
    const int wm = wv >> 2, wn = wv & 3;
    const int rb = blockIdx.x * 32;
    const int b_ = rb >> 11, tile = (rb & (TT - 1)) >> 5;

    // staging: row = tid>>4 (0..31), 16 f32 at col (tid&15)*16 (chunk-relative)
    const int srow = tid >> 4, sc = (tid & 15) * 16;
    const float* xsrc = &x[(size_t)(rb + srow) * CC + sc];
    const int swz = (srow & 15) << 3;
    const int wg0 = srow * 256 + (sc ^ swz);
    const int wg1 = srow * 256 + ((sc + 8) ^ swz);

    // A-frag read base: row = wm*16 + lo
    const int arow = wm * 16 + lo;
    const int abase = arow * 256;
    const int aswz = (arow & 15) << 3;

    f32x4 acc[3];
#pragma unroll
    for (int n = 0; n < 3; ++n) acc[n] = (f32x4){0.f, 0.f, 0.f, 0.f};

    // prefetch x chunk 0 (16 f32)
    f32x4 pf[4];
#pragma unroll
    for (int i = 0; i < 4; ++i) pf[i] = *reinterpret_cast<const f32x4*>(xsrc + 4 * i);

    // B pipeline: 3 reg sets over 32 slots (slot s -> set s%3), 2-ahead
    s16x8 bv[3][3];
#define BLOAD(SET, SLOT)                                                       \
    {                                                                          \
        _Pragma("unroll")                                                      \
        for (int n = 0; n < 3; ++n)                                            \
            bv[SET][n] = *reinterpret_cast<const s16x8*>(                      \
                &wTf[(((size_t)(wn * 3 + n) * 32 + (SLOT)) * 64 + lane) * 8]); \
    }
    BLOAD(0, 0)
    BLOAD(1, 1)

#pragma unroll
    for (int c = 0; c < 4; ++c) {
        // write staged chunk c (from pf regs) into xb[c&1]
        unsigned short* wb = xb[c & 1];
        s16x8 w0, w1;
        w0[0] = (short)f2bf(pf[0][0]); w0[1] = (short)f2bf(pf[0][1]);
        w0[2] = (short)f2bf(pf[0][2]); w0[3] = (short)f2bf(pf[0][3]);
        w0[4] = (short)f2bf(pf[1][0]); w0[5] = (short)f2bf(pf[1][1]);
        w0[6] = (short)f2bf(pf[1][2]); w0[7] = (short)f2bf(pf[1][3]);
        w1[0] = (short)f2bf(pf[2][0]); w1[1] = (short)f2bf(pf[2][1]);
        w1[2] = (short)f2bf(pf[2][2]); w1[3] = (short)f2bf(pf[2][3]);
        w1[4] = (short)f2bf(pf[3][0]); w1[5] = (short)f2bf(pf[3][1]);
        w1[6] = (short)f2bf(pf[3][2]); w1[7] = (short)f2bf(pf[3][3]);
        *reinterpret_cast<s16x8*>(&wb[wg0]) = w0;
        *reinterpret_cast<s16x8*>(&wb[wg1]) = w1;
        __syncthreads();
        // issue next chunk's x loads (land during this chunk's compute)
        if (c < 3) {
#pragma unroll
            for (int i = 0; i < 4; ++i)
                pf[i] = *reinterpret_cast<const f32x4*>(xsrc + (c + 1) * 256 + 4 * i);
        }
        const unsigned short* base = xb[c & 1];
#pragma unroll
        for (int kh = 0; kh < 8; ++kh) {
            const int slot = c * 8 + kh;
            if (slot + 2 < 32) BLOAD((slot + 2) % 3, slot + 2)
            const s16x8 a = *reinterpret_cast<const s16x8*>(
                &base[abase + ((kh * 32 + hi * 8) ^ aswz)]);
#pragma unroll
            for (int n = 0; n < 3; ++n)
                acc[n] = __builtin_amdgcn_mfma_f32_16x16x32_bf16(a, bv[slot % 3][n], acc[n], 0, 0, 0);
        }
    }
#undef BLOAD

    // ---- Epilogue: acc -> LDS fragment image -> coalesced stores ----
    __syncthreads();   // mainloop LDS reads done; reuse xb
    unsigned short* fr = reinterpret_cast<unsigned short*>(xb);
    // regions (elems): Q [0,2048), K [2048,4096), V [4096,6144)
#pragma unroll
    for (int n = 0; n < 3; ++n) {
        const int n16 = wn * 3 + n;
        const int sel = n16 >> 2;
#pragma unroll
        for (int r = 0; r < 4; ++r) {
            const int tok31 = wm * 16 + 4 * hi + r;
            const unsigned short bvv = f2bf(acc[n][r]);
            if (sel == 0) {
                const int s = n16, half = (lo >> 3) & 1, j = lo & 7;
                fr[(s * 64 + half * 32 + tok31) * 8 + j] = bvv;
            } else if (sel == 1) {
                const int s = n16 - 4, half = (lo >> 3) & 1, j = lo & 7;
                fr[2048 + (s * 64 + half * 32 + tok31) * 8 + j] = bvv;
            } else {
                const int h = (n16 - 8) * 16 + lo;
                const int mt = h >> 5;
                const int s2 = tok31 >> 4, hf = (tok31 >> 3) & 1, jj = tok31 & 7;
                fr[4096 + ((mt * 2 + s2) * 64 + hf * 32 + (h & 31)) * 8 + jj] = bvv;
            }
        }
    }
    __syncthreads();
    const size_t tb = ((size_t)b_ * 64 + tile) * 2048;   // elem base per buffer
    if (tid < 256) {
        *reinterpret_cast<s16x8*>(&Qf[tb + tid * 8]) =
            *reinterpret_cast<const s16x8*>(&fr[tid * 8]);
    } else {
        *reinterpret_cast<s16x8*>(&Kf[tb + (tid - 256) * 8]) =
            *reinterpret_cast<const s16x8*>(&fr[2048 + (tid - 256) * 8]);
    }
    if (tid < 256) {
        *reinterpret_cast<s16x8*>(&Vf[tb + tid * 8]) =
            *reinterpret_cast<const s16x8*>(&fr[4096 + tid * 8]);
    }
}

// ---------------------------------------------------------------------------
// Kernel 2: flash attention (round-7 structure, unchanged).
// 512 blocks (8 batch x 64 q-tiles of 32 rows) x 8 waves, kv tiles strided.
// ---------------------------------------------------------------------------
__global__ __launch_bounds__(512, 4) void attn_kernel(
    const unsigned short* __restrict__ Qf, const unsigned short* __restrict__ Kf,
    const unsigned short* __restrict__ Vf, float* __restrict__ out) {
    __shared__ __align__(16) char smem[33792 + 2048];   // 35.8 KB
    float (*OfL)[64][33] = reinterpret_cast<float(*)[64][33]>(smem);   // 4 slots
    float (*Mm)[32] = reinterpret_cast<float(*)[32]>(smem + 33792);
    float (*Ml)[32] = reinterpret_cast<float(*)[32]>(smem + 33792 + 1024);

    const int tid = threadIdx.x;
    const int wv = tid >> 6, lane = tid & 63;
    const int q = lane & 31, half = lane >> 5;
    const int b = blockIdx.x & 7;              // batch -> XCD L2 locality
    const int qt = 63 - (blockIdx.x >> 3);     // largest work first
    const int qbase = qt * 32;
    const float CEXP = 0.125f * 1.44269504f;   // scale * log2(e)

    // Q fragments: one 1KB coalesced load per s
    const unsigned short* qp = &Qf[(((size_t)b * 64 + qt) * 256 + lane) * 8];
    s16x8 qf[4];
#pragma unroll
    for (int s = 0; s < 4; ++s) qf[s] = *reinterpret_cast<const s16x8*>(qp + s * 512);

    f32x16 oA, oB;   // O^T h-blocks [0..31],[32..63]; lane holds col q
#pragma unroll
    for (int r = 0; r < 16; ++r) { oA[r] = 0.f; oB[r] = 0.f; }
    float m = -1e30f, l = 0.f;   // raw-score domain

    for (int t = wv; t <= qt; t += 8) {
        // V fragments (issued early, contiguous)
        const unsigned short* vp = &Vf[(((size_t)b * 64 + t) * 256 + lane) * 8];
        s16x8 vf[4];
#pragma unroll
        for (int i = 0; i < 4; ++i)
            vf[i] = *reinterpret_cast<const s16x8*>(vp + i * 512);
        // K fragments + QK^T -> S^T[key][q]
        const unsigned short* kp = &Kf[(((size_t)b * 64 + t) * 256 + lane) * 8];
        f32x16 sa;
#pragma unroll
        for (int r = 0; r < 16; ++r) sa[r] = 0.f;
#pragma unroll
        for (int s = 0; s < 4; ++s) {
            const s16x8 kf = *reinterpret_cast<const s16x8*>(kp + s * 512);
            sa = __builtin_amdgcn_mfma_f32_32x32x16_bf16(kf, qf[s], sa, 0, 0, 0);
        }
        // causal mask on diagonal tile: key(r) = 4*half + (r&3) + 8*(r>>2)
        if (t == qt) {
#pragma unroll
            for (int r = 0; r < 16; ++r) {
                const int key = 4 * half + (r & 3) + 8 * (r >> 2);
                if (key > q) sa[r] = -1e30f;
            }
        }
        // row max: in-lane tree + partner exchange
        float pmax = sa[0];
#pragma unroll
        for (int r = 1; r < 16; ++r) pmax = fmaxf(pmax, sa[r]);
        pmax = fmaxf(pmax, __shfl_xor(pmax, 32));
        // defer-max: raw thr 64 = 8 in exp units -> P bounded by e^8
        if (!__all(pmax <= m + 64.f)) {
            const float mnew = fmaxf(m, pmax);
            const float alpha = exp2f((m - mnew) * CEXP);
            l *= alpha;
#pragma unroll
            for (int r = 0; r < 16; ++r) { oA[r] *= alpha; oB[r] *= alpha; }
            m = mnew;
        }
        // exp + row sum
        float rs = 0.f;
#pragma unroll
        for (int r = 0; r < 16; ++r) {
            const float p = exp2f((sa[r] - m) * CEXP);
            sa[r] = p;
            rs += p;
        }
        l += rs + __shfl_xor(rs, 32);
        // pack P -> bf16 pairs; exchange only the 4 words the partner needs
        unsigned d[8];
#pragma unroll
        for (int i = 0; i < 8; ++i) d[i] = cvt_pk_bf16(sa[2 * i], sa[2 * i + 1]);
        const unsigned snd0 = half ? d[0] : d[2];
        const unsigned snd1 = half ? d[1] : d[3];
        const unsigned snd2 = half ? d[4] : d[6];
        const unsigned snd3 = half ? d[5] : d[7];
        const unsigned rcv0 = __shfl_xor(snd0, 32);
        const unsigned rcv1 = __shfl_xor(snd1, 32);
        const unsigned rcv2 = __shfl_xor(snd2, 32);
        const unsigned rcv3 = __shfl_xor(snd3, 32);
        union { unsigned u[4]; s16x8 v; } f0, f1;
        f0.u[0] = half ? rcv0 : d[0];
        f0.u[1] = half ? rcv1 : d[1];
        f0.u[2] = half ? d[2] : rcv0;
        f0.u[3] = half ? d[3] : rcv1;
        f1.u[0] = half ? rcv2 : d[4];
        f1.u[1] = half ? rcv3 : d[5];
        f1.u[2] = half ? d[6] : rcv2;
        f1.u[3] = half ? d[7] : rcv3;
        // PV: O^T += V^T @ P^T  (two K=16 steps, two h-blocks)
        oA = __builtin_amdgcn_mfma_f32_32x32x16_bf16(vf[0], f0.v, oA, 0, 0, 0);
        oB = __builtin_amdgcn_mfma_f32_32x32x16_bf16(vf[2], f0.v, oB, 0, 0, 0);
        oA = __builtin_amdgcn_mfma_f32_32x32x16_bf16(vf[1], f1.v, oA, 0, 0, 0);
        oB = __builtin_amdgcn_mfma_f32_32x32x16_bf16(vf[3], f1.v, oB, 0, 0, 0);
    }

    // ---- tree combine of 8 partials ----
#define PUBLISH(slot)                                                      \
    {                                                                      \
        _Pragma("unroll")                                                  \
        for (int r = 0; r < 16; ++r) {                                     \
            const int h0 = (r & 3) + 8 * (r >> 2) + 4 * half;              \
            OfL[slot][h0][q] = oA[r];                                      \
            OfL[slot][h0 + 32][q] = oB[r];                                 \
        }                                                                  \
    }
#define MERGE(slot, srcw)                                                  \
    {                                                                      \
        const float mb = Mm[srcw][q], lb = Ml[srcw][q];                    \
        const float M = fmaxf(m, mb);                                      \
        const float wa = exp2f((m - M) * CEXP);                            \
        const float wb = exp2f((mb - M) * CEXP);                           \
        _Pragma("unroll")                                                  \
        for (int r = 0; r < 16; ++r) {                                     \
            const int h0 = (r & 3) + 8 * (r >> 2) + 4 * half;              \
            oA[r] = oA[r] * wa + OfL[slot][h0][q] * wb;                    \
            oB[r] = oB[r] * wa + OfL[slot][h0 + 32][q] * wb;               \
        }                                                                  \
        l = l * wa + lb * wb;                                              \
        m = M;                                                             \
    }

    if (lane < 32) { Mm[wv][q] = m; Ml[wv][q] = l; }
    if (wv >= 4) PUBLISH(wv - 4);
    __syncthreads();
    if (wv < 4) MERGE(wv, wv + 4);
    __syncthreads();
    if (wv == 2 || wv == 3) {
        PUBLISH(wv - 2);
        if (lane < 32) { Mm[wv][q] = m; Ml[wv][q] = l; }
    }
    __syncthreads();
    if (wv < 2) MERGE(wv, wv + 2);
    __syncthreads();
    if (wv == 1) {
        PUBLISH(1);
        if (lane < 32) { Mm[1][q] = m; Ml[1][q] = l; }
    }
    __syncthreads();
    if (wv == 0) {
        MERGE(1, 1);
        const float inv = 1.f / l;
#pragma unroll
        for (int r = 0; r < 16; ++r) {
            const int h0 = (r & 3) + 8 * (r >> 2) + 4 * half;
            OfL[0][h0][q] = oA[r] * inv;
            OfL[0][h0 + 32][q] = oB[r] * inv;
        }
    }
    __syncthreads();
    // coalesced final write
#pragma unroll
    for (int i = 0; i < 4; ++i) {
        const int idx = tid + 512 * i;
        const int h = idx & 63, q2 = idx >> 6;
        out[((size_t)b * TT + qbase + q2) * HH + h] = OfL[0][h][q2];
    }
#undef PUBLISH
#undef MERGE
}

extern "C" void kernel_launch(void* const* d_in, const int* in_sizes, int n_in,
                              void* d_out, int out_size, void* d_ws, size_t ws_size,
                              hipStream_t stream) {
    (void)in_sizes; (void)n_in; (void)out_size; (void)ws_size;
    const float* x  = (const float*)d_in[0];
    const float* Wq = (const float*)d_in[1];
    const float* Wk = (const float*)d_in[2];
    const float* Wv = (const float*)d_in[3];
    float* out = (float*)d_out;

    char* ws = (char*)d_ws;
    unsigned short* wTf = (unsigned short*)ws;                      // 384 KB
    unsigned short* Qf  = (unsigned short*)(ws + 393216);           // 2 MB
    unsigned short* Kf  = (unsigned short*)(ws + 393216 + 2097152); // 2 MB
    unsigned short* Vf  = (unsigned short*)(ws + 393216 + 4194304); // 2 MB

    wt_kernel<<<96, 256, 0, stream>>>(Wq, Wk, Wv, wTf);
    qkv_kernel<<<512, 512, 0, stream>>>(x, wTf, Qf, Kf, Vf);
    attn_kernel<<<512, 512, 0, stream>>>(Qf, Kf, Vf, out);
}

// Round 11
// 42.908 us; speedup vs baseline: 4.3876x; 1.2315x over previous
//
#include <hip/hip_runtime.h>
#include <hip/hip_bf16.h>

// Problem constants
#define BB 8
#define TT 2048
#define CC 1024
#define HH 64

typedef float f32x4 __attribute__((ext_vector_type(4)));
typedef float f32x16 __attribute__((ext_vector_type(16)));
typedef short s16x8 __attribute__((ext_vector_type(8)));   // 8 bf16 in 4 VGPRs

// fp32 -> bf16 (RNE), pure bit math
static __device__ __forceinline__ unsigned short f2bf(float f) {
    unsigned int u = __float_as_uint(f);
    u = (u + 0x7FFFu + ((u >> 16) & 1u)) >> 16;
    return (unsigned short)u;
}

// pack two f32 -> 2 bf16 in one dword (RNE); dst.lo = src0, dst.hi = src1
static __device__ __forceinline__ unsigned cvt_pk_bf16(float lo, float hi) {
    unsigned r;
    asm("v_cvt_pk_bf16_f32 %0, %1, %2" : "=v"(r) : "v"(lo), "v"(hi));
    return r;
}

// ---------------------------------------------------------------------------
// Kernel 0: pack Wq|Wk|Wv [1024][64] fp32 into MFMA B-fragment order, bf16.
// ---------------------------------------------------------------------------
__global__ __launch_bounds__(256) void wt_kernel(
    const float* __restrict__ Wq, const float* __restrict__ Wk,
    const float* __restrict__ Wv, unsigned short* __restrict__ wTf) {
    const int e8 = blockIdx.x * 256 + threadIdx.x;
    const int lane = e8 & 63;
    const int s = (e8 >> 6) & 31;
    const int n16 = e8 >> 11;        // 0..11
    const int sel = n16 >> 2;
    const float* W = (sel == 0) ? Wq : ((sel == 1) ? Wk : Wv);
    const int h = ((n16 & 3) << 4) + (lane & 15);
    const int cb = s * 32 + ((lane >> 4) << 3);
    s16x8 v;
#pragma unroll
    for (int j = 0; j < 8; ++j) v[j] = (short)f2bf(W[(size_t)(cb + j) * HH + h]);
    *reinterpret_cast<s16x8*>(&wTf[(size_t)e8 * 8]) = v;
}

// ---------------------------------------------------------------------------
// Kernel 1: QKV projection GEMM v6.
// 256 blocks x 8 waves; block = 64 rows (2 attn tiles). Wave (wm,wn): 32 rows
// (2 M-frags; B reused across both) x 48 cols. BK=128, 8 chunks, dbuf LDS,
// ONE barrier/chunk. B pipeline 4-deep (hides L2 latency), x prefetch 2
// chunks ahead (hides HBM latency). Epilogue: acc -> LDS fragment image ->
// coalesced stores (no write amplification).
// ---------------------------------------------------------------------------
__global__ __launch_bounds__(512, 2) void qkv_kernel(
    const float* __restrict__ x, const unsigned short* __restrict__ wTf,
    unsigned short* __restrict__ Qf, unsigned short* __restrict__ Kf,
    unsigned short* __restrict__ Vf) {
    __shared__ unsigned short xb[2][64 * 128];   // 2 x 16 KB bf16, XOR-swizzled
    const int tid = threadIdx.x;
    const int wv = tid >> 6, lane = tid & 63;
    const int lo = lane & 15, hi = lane >> 4;
    const int wm = wv >> 2, wn = wv & 3;
    const int rb = blockIdx.x * 64;

    // staging: row = tid>>3 (0..63), 16 f32 at col (tid&7)*16 (chunk-relative)
    const int srow = tid >> 3, sc = (tid & 7) * 16;
    const float* xsrc = &x[(size_t)(rb + srow) * CC + sc];
    const int swz = (srow & 7) << 3;
    const int wg0 = srow * 128 + (sc ^ swz);
    const int wg1 = srow * 128 + ((sc + 8) ^ swz);

    // A-frag read bases: rows wm*32 + {0,16} + lo
    const int ar0 = (wm * 32 + lo) * 128;
    const int ar1 = ar0 + 16 * 128;
    const int aswz = (lo & 7) << 3;

    f32x4 acc[2][3];
#pragma unroll
    for (int m = 0; m < 2; ++m)
#pragma unroll
        for (int n = 0; n < 3; ++n) acc[m][n] = (f32x4){0.f, 0.f, 0.f, 0.f};

    // x prefetch, 2 chunks deep (two independent register sets)
    f32x4 pfA[4], pfB[4];
#pragma unroll
    for (int i = 0; i < 4; ++i) pfA[i] = *reinterpret_cast<const f32x4*>(xsrc + 4 * i);
#pragma unroll
    for (int i = 0; i < 4; ++i) pfB[i] = *reinterpret_cast<const f32x4*>(xsrc + 128 + 4 * i);

    // B pipeline: 4 reg sets over 32 slots (slot -> set slot&3), 3-ahead
    s16x8 bv[4][3];
#define BLOAD(SET, SLOT)                                                       \
    {                                                                          \
        _Pragma("unroll")                                                      \
        for (int n = 0; n < 3; ++n)                                            \
            bv[SET][n] = *reinterpret_cast<const s16x8*>(                      \
                &wTf[(((size_t)(wn * 3 + n) * 32 + (SLOT)) * 64 + lane) * 8]); \
    }
    BLOAD(0, 0)
    BLOAD(1, 1)
    BLOAD(2, 2)

#pragma unroll
    for (int c = 0; c < 8; ++c) {
        // write staged chunk c (from its pf set) into xb[c&1]
        unsigned short* wb = xb[c & 1];
        {
            const f32x4* pf = (c & 1) ? pfB : pfA;
            s16x8 w0, w1;
            w0[0] = (short)f2bf(pf[0][0]); w0[1] = (short)f2bf(pf[0][1]);
            w0[2] = (short)f2bf(pf[0][2]); w0[3] = (short)f2bf(pf[0][3]);
            w0[4] = (short)f2bf(pf[1][0]); w0[5] = (short)f2bf(pf[1][1]);
            w0[6] = (short)f2bf(pf[1][2]); w0[7] = (short)f2bf(pf[1][3]);
            w1[0] = (short)f2bf(pf[2][0]); w1[1] = (short)f2bf(pf[2][1]);
            w1[2] = (short)f2bf(pf[2][2]); w1[3] = (short)f2bf(pf[2][3]);
            w1[4] = (short)f2bf(pf[3][0]); w1[5] = (short)f2bf(pf[3][1]);
            w1[6] = (short)f2bf(pf[3][2]); w1[7] = (short)f2bf(pf[3][3]);
            *reinterpret_cast<s16x8*>(&wb[wg0]) = w0;
            *reinterpret_cast<s16x8*>(&wb[wg1]) = w1;
        }
        __syncthreads();
        // issue chunk c+2's x loads into the freed pf set (2-deep in flight)
        if (c < 6) {
            if (c & 1) {
#pragma unroll
                for (int i = 0; i < 4; ++i)
                    pfB[i] = *reinterpret_cast<const f32x4*>(xsrc + (c + 2) * 128 + 4 * i);
            } else {
#pragma unroll
                for (int i = 0; i < 4; ++i)
                    pfA[i] = *reinterpret_cast<const f32x4*>(xsrc + (c + 2) * 128 + 4 * i);
            }
        }
        const unsigned short* base = xb[c & 1];
#pragma unroll
        for (int kh = 0; kh < 4; ++kh) {
            const int slot = c * 4 + kh;
            if (slot + 3 < 32) BLOAD((slot + 3) & 3, slot + 3)
            const s16x8 a0 = *reinterpret_cast<const s16x8*>(
                &base[ar0 + ((kh * 32 + hi * 8) ^ aswz)]);
            const s16x8 a1 = *reinterpret_cast<const s16x8*>(
                &base[ar1 + ((kh * 32 + hi * 8) ^ aswz)]);
#pragma unroll
            for (int n = 0; n < 3; ++n) {
                acc[0][n] = __builtin_amdgcn_mfma_f32_16x16x32_bf16(a0, bv[slot & 3][n], acc[0][n], 0, 0, 0);
                acc[1][n] = __builtin_amdgcn_mfma_f32_16x16x32_bf16(a1, bv[slot & 3][n], acc[1][n], 0, 0, 0);
            }
        }
        // single barrier per chunk: next write targets the OTHER buffer, and
        // the barrier at iter c+1 (which drains lgkm) protects reuse at c+2.
    }
#undef BLOAD

    // ---- Epilogue: acc -> LDS fragment image -> coalesced stores ----
    __syncthreads();   // mainloop LDS reads done; reuse xb as image
    unsigned short* fr = reinterpret_cast<unsigned short*>(xb);
    // image: per tile-in-block (0/1): base=tib*6144; Q [0,2048) K [2048,4096) V [4096,6144)
#pragma unroll
    for (int n = 0; n < 3; ++n) {
        const int n16 = wn * 3 + n;
        const int sel = n16 >> 2;
#pragma unroll
        for (int m = 0; m < 2; ++m) {
#pragma unroll
            for (int r = 0; r < 4; ++r) {
                const int row64 = wm * 32 + m * 16 + 4 * hi + r;
                const int tib = row64 >> 5, tok31 = row64 & 31;
                const int ib = tib * 6144;
                const unsigned short bvv = f2bf(acc[m][n][r]);
                if (sel == 0) {
                    const int s = n16, half = (lo >> 3) & 1, j = lo & 7;
                    fr[ib + (s * 64 + half * 32 + tok31) * 8 + j] = bvv;
                } else if (sel == 1) {
                    const int s = n16 - 4, half = (lo >> 3) & 1, j = lo & 7;
                    fr[ib + 2048 + (s * 64 + half * 32 + tok31) * 8 + j] = bvv;
                } else {
                    const int h = (n16 - 8) * 16 + lo;
                    const int mt = h >> 5;
                    const int s2 = tok31 >> 4, hf = (tok31 >> 3) & 1, jj = tok31 & 7;
                    fr[ib + 4096 + ((mt * 2 + s2) * 64 + hf * 32 + (h & 31)) * 8 + jj] = bvv;
                }
            }
        }
    }
    __syncthreads();
    // copy out: 1536 groups x 8 elems (24 KB), fully coalesced 16B stores
    const int b_ = rb >> 11;
    const int tile0 = (rb & (TT - 1)) >> 5;
#pragma unroll
    for (int i = 0; i < 3; ++i) {
        const int g = tid + 512 * i;            // 0..1535
        const int tib = (g >= 768) ? 1 : 0;
        const int rem = g - tib * 768;
        const int buf = rem >> 8;               // 0=Q 1=K 2=V
        const int off = rem & 255;
        const s16x8 val = *reinterpret_cast<const s16x8*>(
            &fr[tib * 6144 + buf * 2048 + off * 8]);
        unsigned short* dst = (buf == 0) ? Qf : ((buf == 1) ? Kf : Vf);
        *reinterpret_cast<s16x8*>(
            &dst[((size_t)b_ * 64 + tile0 + tib) * 2048 + off * 8]) = val;
    }
}

// ---------------------------------------------------------------------------
// Kernel 2: flash attention (round-7 structure, unchanged).
// 512 blocks (8 batch x 64 q-tiles of 32 rows) x 8 waves, kv tiles strided.
// ---------------------------------------------------------------------------
__global__ __launch_bounds__(512, 4) void attn_kernel(
    const unsigned short* __restrict__ Qf, const unsigned short* __restrict__ Kf,
    const unsigned short* __restrict__ Vf, float* __restrict__ out) {
    __shared__ __align__(16) char smem[33792 + 2048];   // 35.8 KB
    float (*OfL)[64][33] = reinterpret_cast<float(*)[64][33]>(smem);   // 4 slots
    float (*Mm)[32] = reinterpret_cast<float(*)[32]>(smem + 33792);
    float (*Ml)[32] = reinterpret_cast<float(*)[32]>(smem + 33792 + 1024);

    const int tid = threadIdx.x;
    const int wv = tid >> 6, lane = tid & 63;
    const int q = lane & 31, half = lane >> 5;
    const int b = blockIdx.x & 7;              // batch -> XCD L2 locality
    const int qt = 63 - (blockIdx.x >> 3);     // largest work first
    const int qbase = qt * 32;
    const float CEXP = 0.125f * 1.44269504f;   // scale * log2(e)

    // Q fragments: one 1KB coalesced load per s
    const unsigned short* qp = &Qf[(((size_t)b * 64 + qt) * 256 + lane) * 8];
    s16x8 qf[4];
#pragma unroll
    for (int s = 0; s < 4; ++s) qf[s] = *reinterpret_cast<const s16x8*>(qp + s * 512);

    f32x16 oA, oB;   // O^T h-blocks [0..31],[32..63]; lane holds col q
#pragma unroll
    for (int r = 0; r < 16; ++r) { oA[r] = 0.f; oB[r] = 0.f; }
    float m = -1e30f, l = 0.f;   // raw-score domain

    for (int t = wv; t <= qt; t += 8) {
        // V fragments (issued early, contiguous)
        const unsigned short* vp = &Vf[(((size_t)b * 64 + t) * 256 + lane) * 8];
        s16x8 vf[4];
#pragma unroll
        for (int i = 0; i < 4; ++i)
            vf[i] = *reinterpret_cast<const s16x8*>(vp + i * 512);
        // K fragments + QK^T -> S^T[key][q]
        const unsigned short* kp = &Kf[(((size_t)b * 64 + t) * 256 + lane) * 8];
        f32x16 sa;
#pragma unroll
        for (int r = 0; r < 16; ++r) sa[r] = 0.f;
#pragma unroll
        for (int s = 0; s < 4; ++s) {
            const s16x8 kf = *reinterpret_cast<const s16x8*>(kp + s * 512);
            sa = __builtin_amdgcn_mfma_f32_32x32x16_bf16(kf, qf[s], sa, 0, 0, 0);
        }
        // causal mask on diagonal tile: key(r) = 4*half + (r&3) + 8*(r>>2)
        if (t == qt) {
#pragma unroll
            for (int r = 0; r < 16; ++r) {
                const int key = 4 * half + (r & 3) + 8 * (r >> 2);
                if (key > q) sa[r] = -1e30f;
            }
        }
        // row max: in-lane tree + partner exchange
        float pmax = sa[0];
#pragma unroll
        for (int r = 1; r < 16; ++r) pmax = fmaxf(pmax, sa[r]);
        pmax = fmaxf(pmax, __shfl_xor(pmax, 32));
        // defer-max: raw thr 64 = 8 in exp units -> P bounded by e^8
        if (!__all(pmax <= m + 64.f)) {
            const float mnew = fmaxf(m, pmax);
            const float alpha = exp2f((m - mnew) * CEXP);
            l *= alpha;
#pragma unroll
            for (int r = 0; r < 16; ++r) { oA[r] *= alpha; oB[r] *= alpha; }
            m = mnew;
        }
        // exp + row sum
        float rs = 0.f;
#pragma unroll
        for (int r = 0; r < 16; ++r) {
            const float p = exp2f((sa[r] - m) * CEXP);
            sa[r] = p;
            rs += p;
        }
        l += rs + __shfl_xor(rs, 32);
        // pack P -> bf16 pairs; exchange only the 4 words the partner needs
        unsigned d[8];
#pragma unroll
        for (int i = 0; i < 8; ++i) d[i] = cvt_pk_bf16(sa[2 * i], sa[2 * i + 1]);
        const unsigned snd0 = half ? d[0] : d[2];
        const unsigned snd1 = half ? d[1] : d[3];
        const unsigned snd2 = half ? d[4] : d[6];
        const unsigned snd3 = half ? d[5] : d[7];
        const unsigned rcv0 = __shfl_xor(snd0, 32);
        const unsigned rcv1 = __shfl_xor(snd1, 32);
        const unsigned rcv2 = __shfl_xor(snd2, 32);
        const unsigned rcv3 = __shfl_xor(snd3, 32);
        union { unsigned u[4]; s16x8 v; } f0, f1;
        f0.u[0] = half ? rcv0 : d[0];
        f0.u[1] = half ? rcv1 : d[1];
        f0.u[2] = half ? d[2] : rcv0;
        f0.u[3] = half ? d[3] : rcv1;
        f1.u[0] = half ? rcv2 : d[4];
        f1.u[1] = half ? rcv3 : d[5];
        f1.u[2] = half ? d[6] : rcv2;
        f1.u[3] = half ? d[7] : rcv3;
        // PV: O^T += V^T @ P^T  (two K=16 steps, two h-blocks)
        oA = __builtin_amdgcn_mfma_f32_32x32x16_bf16(vf[0], f0.v, oA, 0, 0, 0);
        oB = __builtin_amdgcn_mfma_f32_32x32x16_bf16(vf[2], f0.v, oB, 0, 0, 0);
        oA = __builtin_amdgcn_mfma_f32_32x32x16_bf16(vf[1], f1.v, oA, 0, 0, 0);
        oB = __builtin_amdgcn_mfma_f32_32x32x16_bf16(vf[3], f1.v, oB, 0, 0, 0);
    }

    // ---- tree combine of 8 partials ----
#define PUBLISH(slot)                                                      \
    {                                                                      \
        _Pragma("unroll")                                                  \
        for (int r = 0; r < 16; ++r) {                                     \
            const int h0 = (r & 3) + 8 * (r >> 2) + 4 * half;              \
            OfL[slot][h0][q] = oA[r];                                      \
            OfL[slot][h0 + 32][q] = oB[r];                                 \
        }                                                                  \
    }
#define MERGE(slot, srcw)                                                  \
    {                                                                      \
        const float mb = Mm[srcw][q], lb = Ml[srcw][q];                    \
        const float M = fmaxf(m, mb);                                      \
        const float wa = exp2f((m - M) * CEXP);                            \
        const float wb = exp2f((mb - M) * CEXP);                           \
        _Pragma("unroll")                                                  \
        for (int r = 0; r < 16; ++r) {                                     \
            const int h0 = (r & 3) + 8 * (r >> 2) + 4 * half;              \
            oA[r] = oA[r] * wa + OfL[slot][h0][q] * wb;                    \
            oB[r] = oB[r] * wa + OfL[slot][h0 + 32][q] * wb;               \
        }                                                                  \
        l = l * wa + lb * wb;                                              \
        m = M;                                                             \
    }

    if (lane < 32) { Mm[wv][q] = m; Ml[wv][q] = l; }
    if (wv >= 4) PUBLISH(wv - 4);
    __syncthreads();
    if (wv < 4) MERGE(wv, wv + 4);
    __syncthreads();
    if (wv == 2 || wv == 3) {
        PUBLISH(wv - 2);
        if (lane < 32) { Mm[wv][q] = m; Ml[wv][q] = l; }
    }
    __syncthreads();
    if (wv < 2) MERGE(wv, wv + 2);
    __syncthreads();
    if (wv == 1) {
        PUBLISH(1);
        if (lane < 32) { Mm[1][q] = m; Ml[1][q] = l; }
    }
    __syncthreads();
    if (wv == 0) {
        MERGE(1, 1);
        const float inv = 1.f / l;
#pragma unroll
        for (int r = 0; r < 16; ++r) {
            const int h0 = (r & 3) + 8 * (r >> 2) + 4 * half;
            OfL[0][h0][q] = oA[r] * inv;
            OfL[0][h0 + 32][q] = oB[r] * inv;
        }
    }
    __syncthreads();
    // coalesced final write
#pragma unroll
    for (int i = 0; i < 4; ++i) {
        const int idx = tid + 512 * i;
        const int h = idx & 63, q2 = idx >> 6;
        out[((size_t)b * TT + qbase + q2) * HH + h] = OfL[0][h][q2];
    }
#undef PUBLISH
#undef MERGE
}

extern "C" void kernel_launch(void* const* d_in, const int* in_sizes, int n_in,
                              void* d_out, int out_size, void* d_ws, size_t ws_size,
                              hipStream_t stream) {
    (void)in_sizes; (void)n_in; (void)out_size; (void)ws_size;
    const float* x  = (const float*)d_in[0];
    const float* Wq = (const float*)d_in[1];
    const float* Wk = (const float*)d_in[2];
    const float* Wv = (const float*)d_in[3];
    float* out = (float*)d_out;

    char* ws = (char*)d_ws;
    unsigned short* wTf = (unsigned short*)ws;                      // 384 KB
    unsigned short* Qf  = (unsigned short*)(ws + 393216);           // 2 MB
    unsigned short* Kf  = (unsigned short*)(ws + 393216 + 2097152); // 2 MB
    unsigned short* Vf  = (unsigned short*)(ws + 393216 + 4194304); // 2 MB

    wt_kernel<<<96, 256, 0, stream>>>(Wq, Wk, Wv, wTf);
    qkv_kernel<<<256, 512, 0, stream>>>(x, wTf, Qf, Kf, Vf);
    attn_kernel<<<512, 512, 0, stream>>>(Qf, Kf, Vf, out);
}